// Round 3
// baseline (414.345 us; speedup 1.0000x reference)
//
#include <hip/hip_runtime.h>
#include <hip/hip_bf16.h>
#include <math.h>

#define NN 20000
#define NE 320000
#define C0I 32
#define C1I 16
#define C0O 64
#define C1O 16
#define EPSF 1e-8f
#define STAGE_TOTAL 1671264

using bf16 = __hip_bfloat16;

__device__ __forceinline__ float b2f(bf16 v) { return __bfloat162float(v); }

// ---- kd: dtype detector (f32 inputs read as bf16 show junk exponents) ----
__global__ __launch_bounds__(256) void se3_detect(const void* x0raw, int* flag) {
    __shared__ int s;
    if (threadIdx.x == 0) s = 0;
    __syncthreads();
    const bf16* p = (const bf16*)x0raw;
    bool junk = false;
    for (int i = threadIdx.x * 2; i < 16384; i += 512) {
        float v = b2f(p[i]);
        if (!(fabsf(v) < 1e3f)) junk = true;
    }
    if (junk) atomicOr(&s, 1);
    __syncthreads();
    if (threadIdx.x == 0) *flag = s;
}

// ---- kc: stage all float inputs as f32; also zero the CSR histogram ----
__global__ __launch_bounds__(256) void se3_convert(
    const void* s0, const void* s1, const void* s2, const void* s3,
    const void* s4, const void* s5, const void* s6, const void* s7,
    const void* s8, const void* s9, const void* s10, const void* s11,
    const int* __restrict__ flag, float* __restrict__ dst, int* __restrict__ cnt) {
    const void* srcs[12] = {s0,s1,s2,s3,s4,s5,s6,s7,s8,s9,s10,s11};
    const int cntseg[12] = {640000,960000,60000,2048,2048,1024,2048,1024,512,256,2048,256};
    int isf32 = *flag;
    int stride = gridDim.x * 256;
    for (int i = blockIdx.x * 256 + threadIdx.x; i < STAGE_TOTAL; i += stride) {
        int seg = 0, off = i;
        while (off >= cntseg[seg]) { off -= cntseg[seg]; ++seg; }
        dst[i] = isf32 ? ((const float*)srcs[seg])[off]
                       : b2f(((const bf16*)srcs[seg])[off]);
    }
    for (int i = blockIdx.x * 256 + threadIdx.x; i < NN; i += stride) cnt[i] = 0;
}

// ---- kh: dst histogram + combined attention weights Wqkc[32][48] ----
//      Wqkc[cp][c]    = sum_j Wq0[cp,j] Wk00[c,j]      (c<32)
//      Wqkc[cp][32+c] = sum_j Wq0[cp,j] Wk10[c,j]      (c<16)
__global__ __launch_bounds__(256) void se3_hist(
    const int* __restrict__ ei, int* __restrict__ cnt,
    const float* __restrict__ wq0, const float* __restrict__ wk00,
    const float* __restrict__ wk10, float* __restrict__ wqkc) {
    int gid = blockIdx.x * 256 + threadIdx.x;
    if (gid < 1536) {
        int cp = gid / 48, c = gid % 48;
        float a = 0.f;
        if (c < 32) { for (int j = 0; j < C0O; ++j) a += wq0[cp*C0O+j] * wk00[c*C0O+j]; }
        else        { for (int j = 0; j < C0O; ++j) a += wq0[cp*C0O+j] * wk10[(c-32)*C0O+j]; }
        wqkc[gid] = a;
    }
    if (gid < NE) atomicAdd(&cnt[ei[NE + gid]], 1);
}

// ---- ks: exclusive scan of cnt[NN] -> rowptr, wptr ----
__global__ __launch_bounds__(1024) void se3_scan(
    const int* __restrict__ cnt, int* __restrict__ rowptr, int* __restrict__ wptr) {
    __shared__ int tmp[1024];
    int t = threadIdx.x;
    int base = t * 20;
    int v[20]; int s = 0;
#pragma unroll
    for (int i = 0; i < 20; ++i) {
        int idx = base + i;
        int c = (idx < NN) ? cnt[idx] : 0;
        v[i] = s; s += c;
    }
    tmp[t] = s;
    __syncthreads();
    for (int off = 1; off < 1024; off <<= 1) {
        int x = (t >= off) ? tmp[t - off] : 0;
        __syncthreads();
        tmp[t] += x;
        __syncthreads();
    }
    int tb = (t > 0) ? tmp[t - 1] : 0;
#pragma unroll
    for (int i = 0; i < 20; ++i) {
        int idx = base + i;
        if (idx < NN) { int r = tb + v[i]; rowptr[idx] = r; wptr[idx] = r; }
    }
    if (t == 1023) rowptr[NN] = NE;
}

// ---- kx: scatter src node ids into dst-sorted order ----
__global__ __launch_bounds__(256) void se3_scatter(
    const int* __restrict__ ei, int* __restrict__ wptr, int* __restrict__ csr_src) {
    int e = blockIdx.x * 256 + threadIdx.x;
    if (e >= NE) return;
    int d = ei[NE + e];
    int off = atomicAdd(&wptr[d], 1);
    csr_src[off] = ei[e];
}

// ---- kF: fused per-node attention. One wave per dst node, 4 waves/block. ----
// Aggregates per node (online softmax, register-resident, shuffle reductions):
//   a0[32]  = sum_e w*x0s        (lanes 0-31, reg aggA)
//   dot[16] = sum_e w*x1dot      (lanes 32-47, reg aggA)
//   x1a[48] = sum_e w*x1s        (lanes 0-47, reg aggB)
//   C[32][3]= sum_e w*x0s (x) Y  (lanes 0-31, regs C0..C2)
// Epilogue:  out0[j] = sum_r feat[r]*sM0[r][j],  feat = [a0/z | dot/z | x0n]  (80 rows)
//            out1[f,d] = sum_r G[r][d]*sM1[r][f], G = [x1a/z | C/z | x1n]     (64 rows)
__global__ __launch_bounds__(256) void se3_fused(
    const float* __restrict__ x0, const float* __restrict__ x1,
    const float* __restrict__ pos,
    const float* __restrict__ wv00, const float* __restrict__ wv10,
    const float* __restrict__ wv01, const float* __restrict__ wv11,
    const float* __restrict__ ws0, const float* __restrict__ ws1,
    const float* __restrict__ wqkc,
    const int* __restrict__ rowptr, const int* __restrict__ csr_src,
    const int* __restrict__ flag, void* __restrict__ out) {
    __shared__ float sM0[80][64];   // rows: 0-31 Wv00, 32-47 Wv10, 48-79 Wself0
    __shared__ float sM1[64][16];   // rows: 0-15 Wv11, 16-47 Wv01, 48-63 Wself1
    __shared__ float sQK[1536];     // [32][48] combined q-weights
    __shared__ float sc[4][288];    // per-wave scratch

    int tid = threadIdx.x;
    for (int i = tid; i < 7680; i += 256) {
        if (i < 5120) {
            int r = i >> 6, j = i & 63;
            sM0[r][j] = (r < 32) ? wv00[r * 64 + j]
                       : (r < 48) ? wv10[(r - 32) * 64 + j]
                                  : ws0[(r - 48) * 64 + j];
        } else if (i < 6144) {
            int k = i - 5120; int r = k >> 4, f = k & 15;
            sM1[r][f] = (r < 16) ? wv11[r * 16 + f]
                       : (r < 48) ? wv01[(r - 16) * 16 + f]
                                  : ws1[(r - 48) * 16 + f];
        } else {
            sQK[i - 6144] = wqkc[i - 6144];
        }
    }
    __syncthreads();

    int wv = tid >> 6, lane = tid & 63;
    int n = blockIdx.x * 4 + wv;          // grid is exactly 5000*4 = NN waves
    float* scw = sc[wv];
    int isf32 = *flag;

    float pnx = pos[n * 3 + 0], pny = pos[n * 3 + 1], pnz = pos[n * 3 + 2];
    // stage x0n into scratch rows 48-79 (doubles as feat rows for epilogue)
    if (lane < 32) scw[48 + lane] = x0[n * 32 + lane];
    // per-lane query weights qh[c] (lanes 0-47), broadcast-read x0n from scratch
    float qh = 0.f;
    if (lane < 48) {
        for (int cp = 0; cp < 32; ++cp) qh += scw[48 + cp] * sQK[cp * 48 + lane];
    }

    int p0 = rowptr[n], p1 = rowptr[n + 1];
    float m = -INFINITY, zz = 0.f;
    float aggA = 0.f, aggB = 0.f, Cx = 0.f, Cy = 0.f, Cz = 0.f;
    int cc3 = (lane >= 32 && lane < 48) ? (lane - 32) * 3 : 0;

    for (int p = p0; p < p1; ++p) {
        int s = csr_src[p];
        float x0v = (lane < 32) ? x0[s * 32 + lane] : 0.f;
        float x1v = (lane < 48) ? x1[s * 48 + lane] : 0.f;
        float rx = pnx - pos[s * 3 + 0];
        float ry = pny - pos[s * 3 + 1];
        float rz = pnz - pos[s * 3 + 2];
        float inv = 1.f / (sqrtf(rx * rx + ry * ry + rz * rz) + EPSF);
        float Yx = rx * inv, Yy = ry * inv, Yz = rz * inv;
        // x1dot[c] on lanes 32-47 via shuffles of x1v (layout c*3+d on lanes 0-47)
        float xd = __shfl(x1v, cc3) * Yx + __shfl(x1v, cc3 + 1) * Yy + __shfl(x1v, cc3 + 2) * Yz;
        float part = (lane < 32) ? x0v * qh : ((lane < 48) ? xd * qh : 0.f);
        part += __shfl_xor(part, 1);  part += __shfl_xor(part, 2);
        part += __shfl_xor(part, 4);  part += __shfl_xor(part, 8);
        part += __shfl_xor(part, 16); part += __shfl_xor(part, 32);
        float lg = part * 0.125f;     // 1/sqrt(64)
        // online softmax update
        float nm = fmaxf(m, lg);
        float f0 = __expf(m - nm);    // first iter: exp(-inf)=0
        float w  = __expf(lg - nm);
        m = nm;
        zz = zz * f0 + w;
        float av = (lane < 32) ? x0v : xd;
        aggA = aggA * f0 + w * av;
        aggB = aggB * f0 + w * x1v;
        float wx = w * x0v;
        Cx = Cx * f0 + wx * Yx;
        Cy = Cy * f0 + wx * Yy;
        Cz = Cz * f0 + wx * Yz;
    }

    float invz = 1.f / (zz + EPSF);
    if (lane < 48) {
        scw[lane]       = aggA * invz;        // feat rows 0-47
        scw[96 + lane]  = aggB * invz;        // G rows 0-15 (x1agg), layout c*3+d
        scw[240 + lane] = x1[n * 48 + lane];  // G rows 48-63 (x1n)
    }
    if (lane < 32) {                          // G rows 16-47 (C), base 96+48*... = 144
        scw[144 + lane * 3 + 0] = Cx * invz;
        scw[144 + lane * 3 + 1] = Cy * invz;
        scw[144 + lane * 3 + 2] = Cz * invz;
    }

    // out0: all 64 lanes, j = lane
    float o0 = 0.f;
    for (int r = 0; r < 80; ++r) o0 += scw[r] * sM0[r][lane];
    // out1: lanes 0-47, lane = f*3+d
    int f = lane / 3, d = lane - 3 * f;
    float o1 = 0.f;
    if (lane < 48) {
        for (int r = 0; r < 64; ++r) o1 += scw[96 + r * 3 + d] * sM1[r][f];
    }

    if (isf32) {
        ((float*)out)[n * 64 + lane] = o0;
        if (lane < 48) ((float*)out)[NN * 64 + n * 48 + lane] = o1;
    } else {
        ((bf16*)out)[n * 64 + lane] = __float2bfloat16(o0);
        if (lane < 48) ((bf16*)out)[NN * 64 + n * 48 + lane] = __float2bfloat16(o1);
    }
}

extern "C" void kernel_launch(void* const* d_in, const int* in_sizes, int n_in,
                              void* d_out, int out_size, void* d_ws, size_t ws_size,
                              hipStream_t stream) {
    const int* ei = (const int*)d_in[3];

    int* flag  = (int*)d_ws;
    float* ws  = (float*)d_ws + 16;
    float* x0f  = ws;                 // 640000
    float* x1f  = x0f + 640000;       // 960000
    float* posf = x1f + 960000;       // 60000
    float* wq0    = posf + 60000;     // 2048
    float* wk00   = wq0 + 2048;       // 2048
    float* wk10   = wk00 + 2048;      // 1024
    float* wv00   = wk10 + 1024;      // 2048
    float* wv10   = wv00 + 2048;      // 1024
    float* wv01   = wv10 + 1024;      // 512
    float* wv11   = wv01 + 512;       // 256
    float* wself0 = wv11 + 256;       // 2048
    float* wself1 = wself0 + 2048;    // 256
    float* wqkc = ws + STAGE_TOTAL;   // 1536
    int* cnt     = (int*)(wqkc + 1536);       // NN
    int* rowptr  = cnt + NN;                  // NN+1
    int* wptr    = rowptr + NN + 1;           // NN
    int* csr_src = wptr + NN;                 // NE

    se3_detect<<<1, 256, 0, stream>>>(d_in[0], flag);
    se3_convert<<<512, 256, 0, stream>>>(d_in[0], d_in[1], d_in[2],
        d_in[4], d_in[5], d_in[6], d_in[7], d_in[8], d_in[9], d_in[10], d_in[11], d_in[12],
        flag, ws, cnt);
    se3_hist<<<1250, 256, 0, stream>>>(ei, cnt, wq0, wk00, wk10, wqkc);
    se3_scan<<<1, 1024, 0, stream>>>(cnt, rowptr, wptr);
    se3_scatter<<<1250, 256, 0, stream>>>(ei, wptr, csr_src);
    se3_fused<<<5000, 256, 0, stream>>>(x0f, x1f, posf,
        wv00, wv10, wv01, wv11, wself0, wself1, wqkc,
        rowptr, csr_src, flag, d_out);
}

// Round 4
// 250.573 us; speedup vs baseline: 1.6536x; 1.6536x over previous
//
#include <hip/hip_runtime.h>
#include <hip/hip_bf16.h>
#include <math.h>

#define NN 20000
#define NE 320000
#define C0I 32
#define C1I 16
#define C0O 64
#define C1O 16
#define EPSF 1e-8f
#define STAGE_TOTAL 1671264

using bf16 = __hip_bfloat16;

__device__ __forceinline__ float b2f(bf16 v) { return __bfloat162float(v); }

// ---- kA: detect dtype (per-block, same sample -> same verdict) + stage all
//          float inputs as f32 + zero CSR histogram ----
__global__ __launch_bounds__(256) void se3_convert(
    const void* s0, const void* s1, const void* s2, const void* s3,
    const void* s4, const void* s5, const void* s6, const void* s7,
    const void* s8, const void* s9, const void* s10, const void* s11,
    int* __restrict__ flag, float* __restrict__ dst, int* __restrict__ cnt) {
    __shared__ int sj;
    if (threadIdx.x == 0) sj = 0;
    __syncthreads();
    {   // f32 data read as bf16 shows junk exponents at even indices
        const bf16* p = (const bf16*)s0;
        bool junk = false;
        for (int i = threadIdx.x * 2; i < 16384; i += 512) {
            float v = b2f(p[i]);
            if (!(fabsf(v) < 1e3f)) junk = true;
        }
        if (junk) atomicOr(&sj, 1);
    }
    __syncthreads();
    int isf32 = sj;
    if (blockIdx.x == 0 && threadIdx.x == 0) *flag = isf32;

    const void* srcs[12] = {s0,s1,s2,s3,s4,s5,s6,s7,s8,s9,s10,s11};
    const int cntseg[12] = {640000,960000,60000,2048,2048,1024,2048,1024,512,256,2048,256};
    int stride = gridDim.x * 256;
    for (int i = blockIdx.x * 256 + threadIdx.x; i < STAGE_TOTAL; i += stride) {
        int seg = 0, off = i;
        while (off >= cntseg[seg]) { off -= cntseg[seg]; ++seg; }
        dst[i] = isf32 ? ((const float*)srcs[seg])[off]
                       : b2f(((const bf16*)srcs[seg])[off]);
    }
    for (int i = blockIdx.x * 256 + threadIdx.x; i < NN; i += stride) cnt[i] = 0;
}

// ---- kB: dst histogram + combined attention weights Wqkc[32][48] ----
__global__ __launch_bounds__(256) void se3_hist(
    const int* __restrict__ ei, int* __restrict__ cnt,
    const float* __restrict__ wq0, const float* __restrict__ wk00,
    const float* __restrict__ wk10, float* __restrict__ wqkc) {
    int gid = blockIdx.x * 256 + threadIdx.x;
    if (gid < 1536) {
        int cp = gid / 48, c = gid % 48;
        float a = 0.f;
        if (c < 32) { for (int j = 0; j < C0O; ++j) a += wq0[cp*C0O+j] * wk00[c*C0O+j]; }
        else        { for (int j = 0; j < C0O; ++j) a += wq0[cp*C0O+j] * wk10[(c-32)*C0O+j]; }
        wqkc[gid] = a;
    }
    if (gid < NE) atomicAdd(&cnt[ei[NE + gid]], 1);
}

// ---- kC: exclusive scan of cnt[NN] -> rowptr, wptr ----
__global__ __launch_bounds__(1024) void se3_scan(
    const int* __restrict__ cnt, int* __restrict__ rowptr, int* __restrict__ wptr) {
    __shared__ int tmp[1024];
    int t = threadIdx.x;
    int base = t * 20;
    int v[20]; int s = 0;
#pragma unroll
    for (int i = 0; i < 20; ++i) {
        int idx = base + i;
        int c = (idx < NN) ? cnt[idx] : 0;
        v[i] = s; s += c;
    }
    tmp[t] = s;
    __syncthreads();
    for (int off = 1; off < 1024; off <<= 1) {
        int x = (t >= off) ? tmp[t - off] : 0;
        __syncthreads();
        tmp[t] += x;
        __syncthreads();
    }
    int tb = (t > 0) ? tmp[t - 1] : 0;
#pragma unroll
    for (int i = 0; i < 20; ++i) {
        int idx = base + i;
        if (idx < NN) { int r = tb + v[i]; rowptr[idx] = r; wptr[idx] = r; }
    }
    if (t == 1023) rowptr[NN] = NE;
}

// ---- kD: blocks [0,1250): scatter src ids to CSR; blocks [1250,6250): per-node
//          query vectors qvec[n][c] = sum_cp x0[n,cp]*Wqkc[cp][c] (wave per node) ----
__global__ __launch_bounds__(256) void se3_scatqv(
    const int* __restrict__ ei, int* __restrict__ wptr, int* __restrict__ csr_src,
    const float* __restrict__ x0, const float* __restrict__ wqkc,
    float* __restrict__ qvec) {
    int b = blockIdx.x;
    if (b < 1250) {
        int e = b * 256 + threadIdx.x;
        if (e < NE) {
            int d = ei[NE + e];
            int off = atomicAdd(&wptr[d], 1);
            csr_src[off] = ei[e];
        }
    } else {
        __shared__ float sw[1536];
        for (int i = threadIdx.x; i < 1536; i += 256) sw[i] = wqkc[i];
        __syncthreads();
        int wv = threadIdx.x >> 6, lane = threadIdx.x & 63;
        int n = (b - 1250) * 4 + wv;
        float x0v = (lane < 32) ? x0[n * 32 + lane] : 0.f;
        int li = (lane < 48) ? lane : 0;
        float qh = 0.f;
        for (int cp = 0; cp < 32; ++cp)
            qh += __shfl(x0v, cp) * sw[cp * 48 + li];
        if (lane < 48) qvec[n * 48 + lane] = qh;
    }
}

// ---- kF: fused per-node attention, two-phase (lane=edge logits, lane=feature agg) ----
__global__ __launch_bounds__(256) void se3_fused(
    const float* __restrict__ x0, const float* __restrict__ x1,
    const float* __restrict__ pos,
    const float* __restrict__ wv00, const float* __restrict__ wv10,
    const float* __restrict__ wv01, const float* __restrict__ wv11,
    const float* __restrict__ ws0, const float* __restrict__ ws1,
    const float* __restrict__ qvec,
    const int* __restrict__ rowptr, const int* __restrict__ csr_src,
    const int* __restrict__ flag, void* __restrict__ out) {
    __shared__ float sM0[80][64];   // rows: 0-31 Wv00, 32-47 Wv10, 48-79 Wself0
    __shared__ float sM1[64][16];   // rows: 0-15 Wv11, 16-47 Wv01, 48-63 Wself1
    __shared__ float sc[4][288];    // per-wave: [0-47] qvec->feat, [48-79] x0n, [96-287] G

    int tid = threadIdx.x;
    for (int i = tid; i < 6144; i += 256) {
        if (i < 5120) {
            int r = i >> 6, j = i & 63;
            sM0[r][j] = (r < 32) ? wv00[r * 64 + j]
                       : (r < 48) ? wv10[(r - 32) * 64 + j]
                                  : ws0[(r - 48) * 64 + j];
        } else {
            int k = i - 5120; int r = k >> 4, f = k & 15;
            sM1[r][f] = (r < 16) ? wv11[r * 16 + f]
                       : (r < 48) ? wv01[(r - 16) * 16 + f]
                                  : ws1[(r - 48) * 16 + f];
        }
    }
    __syncthreads();

    int wv = tid >> 6, lane = tid & 63;
    int n = blockIdx.x * 4 + wv;          // grid = 5000 blocks -> exactly NN waves
    float* scw = sc[wv];
    int isf32 = *flag;

    float pnx = pos[n * 3 + 0], pny = pos[n * 3 + 1], pnz = pos[n * 3 + 2];
    if (lane < 32) scw[48 + lane] = x0[n * 32 + lane];   // x0n (feat rows 48-79)
    if (lane < 48) scw[lane] = qvec[n * 48 + lane];      // per-node query weights

    int p0 = rowptr[n], deg = rowptr[n + 1] - p0;
    float m = -INFINITY, zz = 0.f;
    float aggA = 0.f, aggB = 0.f, Cx = 0.f, Cy = 0.f, Cz = 0.f;
    int cc3 = (lane >= 32 && lane < 48) ? (lane - 32) * 3 : 0;

    for (int base = 0; base < deg; base += 64) {
        int nch = min(64, deg - base);
        // ---- Phase A: lane e computes full logit of edge base+e ----
        int s_e = 0;
        float lg = -INFINITY, Yx = 0.f, Yy = 0.f, Yz = 0.f;
        if (lane < nch) {
            s_e = csr_src[p0 + base + lane];
            float rx = pnx - pos[s_e * 3 + 0];
            float ry = pny - pos[s_e * 3 + 1];
            float rz = pnz - pos[s_e * 3 + 2];
            float inv = 1.f / (sqrtf(rx * rx + ry * ry + rz * rz) + EPSF);
            Yx = rx * inv; Yy = ry * inv; Yz = rz * inv;
            const float4* px0 = (const float4*)(x0 + (size_t)s_e * 32);
            float acc = 0.f;
#pragma unroll
            for (int k = 0; k < 8; ++k) {
                float4 v = px0[k];
                acc += v.x * scw[4*k] + v.y * scw[4*k+1] + v.z * scw[4*k+2] + v.w * scw[4*k+3];
            }
            const float4* px1 = (const float4*)(x1 + (size_t)s_e * 48);
#pragma unroll
            for (int g = 0; g < 4; ++g) {          // 3 float4 = channels 4g..4g+3
                float4 a = px1[3*g], b = px1[3*g+1], c = px1[3*g+2];
                float d0 = a.x * Yx + a.y * Yy + a.z * Yz;
                float d1 = a.w * Yx + b.x * Yy + b.y * Yz;
                float d2 = b.z * Yx + b.w * Yy + c.x * Yz;
                float d3 = c.y * Yx + c.z * Yy + c.w * Yz;
                acc += d0 * scw[32+4*g] + d1 * scw[33+4*g] + d2 * scw[34+4*g] + d3 * scw[35+4*g];
            }
            lg = acc * 0.125f;                     // 1/sqrt(64)
        }
        // chunk max / weights / sum (wave-wide)
        float mc = lg;
#pragma unroll
        for (int o = 1; o < 64; o <<= 1) mc = fmaxf(mc, __shfl_xor(mc, o));
        float nm = fmaxf(m, mc);
        float f0 = __expf(m - nm);                 // first chunk: exp(-inf)=0
        float w = (lane < nch) ? __expf(lg - nm) : 0.f;
        float swm = w;
#pragma unroll
        for (int o = 1; o < 64; o <<= 1) swm += __shfl_xor(swm, o);
        zz = zz * f0 + swm;
        m = nm;
        aggA *= f0; aggB *= f0; Cx *= f0; Cy *= f0; Cz *= f0;
        // ---- Phase B: lane = feature channel; independent iterations ----
#pragma unroll 4
        for (int e = 0; e < nch; ++e) {
            float we = __shfl(w, e);
            int se = __shfl(s_e, e);
            float Yex = __shfl(Yx, e), Yey = __shfl(Yy, e), Yez = __shfl(Yz, e);
            float x0v = (lane < 32) ? x0[(size_t)se * 32 + lane] : 0.f;
            float x1v = (lane < 48) ? x1[(size_t)se * 48 + lane] : 0.f;
            float xd = __shfl(x1v, cc3) * Yex + __shfl(x1v, cc3 + 1) * Yey
                     + __shfl(x1v, cc3 + 2) * Yez;
            aggA += we * ((lane < 32) ? x0v : xd);
            aggB += we * x1v;
            float wx = we * x0v;
            Cx += wx * Yex; Cy += wx * Yey; Cz += wx * Yez;
        }
    }

    float invz = 1.f / (zz + EPSF);
    if (lane < 48) {
        scw[lane]       = aggA * invz;        // feat rows 0-47 (overwrites qvec)
        scw[96 + lane]  = aggB * invz;        // G rows 0-15 (x1agg, layout c*3+d)
        scw[240 + lane] = x1[n * 48 + lane];  // G rows 48-63 (x1n)
    }
    if (lane < 32) {                          // G rows 16-47 (C)
        scw[144 + lane * 3 + 0] = Cx * invz;
        scw[144 + lane * 3 + 1] = Cy * invz;
        scw[144 + lane * 3 + 2] = Cz * invz;
    }

    float o0 = 0.f;
    for (int r = 0; r < 80; ++r) o0 += scw[r] * sM0[r][lane];
    int f = lane / 3, d = lane - 3 * f;
    float o1 = 0.f;
    if (lane < 48) {
        for (int r = 0; r < 64; ++r) o1 += scw[96 + r * 3 + d] * sM1[r][f];
    }

    if (isf32) {
        ((float*)out)[n * 64 + lane] = o0;
        if (lane < 48) ((float*)out)[NN * 64 + n * 48 + lane] = o1;
    } else {
        ((bf16*)out)[n * 64 + lane] = __float2bfloat16(o0);
        if (lane < 48) ((bf16*)out)[NN * 64 + n * 48 + lane] = __float2bfloat16(o1);
    }
}

extern "C" void kernel_launch(void* const* d_in, const int* in_sizes, int n_in,
                              void* d_out, int out_size, void* d_ws, size_t ws_size,
                              hipStream_t stream) {
    const int* ei = (const int*)d_in[3];

    int* flag  = (int*)d_ws;
    float* ws  = (float*)d_ws + 16;
    float* x0f  = ws;                 // 640000
    float* x1f  = x0f + 640000;       // 960000
    float* posf = x1f + 960000;       // 60000
    float* wq0    = posf + 60000;     // 2048
    float* wk00   = wq0 + 2048;       // 2048
    float* wk10   = wk00 + 2048;      // 1024
    float* wv00   = wk10 + 1024;      // 2048
    float* wv10   = wv00 + 2048;      // 1024
    float* wv01   = wv10 + 1024;      // 512
    float* wv11   = wv01 + 512;       // 256
    float* wself0 = wv11 + 256;       // 2048
    float* wself1 = wself0 + 2048;    // 256
    float* wqkc = ws + STAGE_TOTAL;   // 1536
    int* cnt     = (int*)(wqkc + 1536);       // NN
    int* rowptr  = cnt + NN;                  // NN+1
    int* wptr    = rowptr + NN + 1;           // NN
    int* csr_src = wptr + NN;                 // NE
    float* qvec  = (float*)(csr_src + NE);    // NN*48

    se3_convert<<<512, 256, 0, stream>>>(d_in[0], d_in[1], d_in[2],
        d_in[4], d_in[5], d_in[6], d_in[7], d_in[8], d_in[9], d_in[10], d_in[11], d_in[12],
        flag, ws, cnt);
    se3_hist<<<1250, 256, 0, stream>>>(ei, cnt, wq0, wk00, wk10, wqkc);
    se3_scan<<<1, 1024, 0, stream>>>(cnt, rowptr, wptr);
    se3_scatqv<<<6250, 256, 0, stream>>>(ei, wptr, csr_src, x0f, wqkc, qvec);
    se3_fused<<<5000, 256, 0, stream>>>(x0f, x1f, posf,
        wv00, wv10, wv01, wv11, wself0, wself1, qvec,
        rowptr, csr_src, flag, d_out);
}

// Round 7
// 209.027 us; speedup vs baseline: 1.9823x; 1.1988x over previous
//
#include <hip/hip_runtime.h>
#include <hip/hip_bf16.h>
#include <math.h>

#define NN 20000
#define NE 320000
#define C0I 32
#define C1I 16
#define C0O 64
#define C1O 16
#define EPSF 1e-8f
#define STAGE_TOTAL 1671264   // total staged f32 elements
#define STAGE_V4    417816    // /4

using bf16 = __hip_bfloat16;

__device__ __forceinline__ float bb2f(unsigned short u) {
    return __uint_as_float(((unsigned)u) << 16);
}

// wave-level LDS fence: drain outstanding ds ops + forbid compile-time motion
__device__ __forceinline__ void lds_fence() {
    asm volatile("s_waitcnt lgkmcnt(0)" ::: "memory");
    __builtin_amdgcn_sched_barrier(0);
}

// ---- kA: detect dtype + stage all float inputs as f32 (vectorized) + zero cnt ----
__global__ __launch_bounds__(256) void se3_convert(
    const void* s0, const void* s1, const void* s2, const void* s3,
    const void* s4, const void* s5, const void* s6, const void* s7,
    const void* s8, const void* s9, const void* s10, const void* s11,
    int* __restrict__ flag, float* __restrict__ dst, int* __restrict__ cnt) {
    __shared__ int sj;
    if (threadIdx.x == 0) sj = 0;
    __syncthreads();
    {   // f32 data read as bf16 at even indices shows junk exponents
        const unsigned short* p = (const unsigned short*)s0;
        bool junk = false;
        int i0 = threadIdx.x * 8;
#pragma unroll
        for (int k = 0; k < 4; ++k) {
            float v = bb2f(p[i0 + k * 2]);
            if (!(fabsf(v) < 1e3f)) junk = true;
        }
        if (junk) atomicOr(&sj, 1);
    }
    __syncthreads();
    int isf32 = sj;
    int gid = blockIdx.x * 256 + threadIdx.x;
    if (gid == 0) *flag = isf32;
    if (gid < NN) cnt[gid] = 0;
    if (gid >= STAGE_V4) return;

    const void* src; int off;  // vec4 units
    if      (gid < 160000) { src = s0;  off = gid; }
    else if (gid < 400000) { src = s1;  off = gid - 160000; }
    else if (gid < 415000) { src = s2;  off = gid - 400000; }
    else if (gid < 415512) { src = s3;  off = gid - 415000; }
    else if (gid < 416024) { src = s4;  off = gid - 415512; }
    else if (gid < 416280) { src = s5;  off = gid - 416024; }
    else if (gid < 416792) { src = s6;  off = gid - 416280; }
    else if (gid < 417048) { src = s7;  off = gid - 416792; }
    else if (gid < 417176) { src = s8;  off = gid - 417048; }
    else if (gid < 417240) { src = s9;  off = gid - 417176; }
    else if (gid < 417752) { src = s10; off = gid - 417240; }
    else                   { src = s11; off = gid - 417752; }

    float4 v;
    if (isf32) {
        v = ((const float4*)src)[off];
    } else {
        ushort4 u = ((const ushort4*)src)[off];
        v = make_float4(bb2f(u.x), bb2f(u.y), bb2f(u.z), bb2f(u.w));
    }
    ((float4*)dst)[gid] = v;
}

// ---- kB: dst histogram + combined attention weights Wqkc[32][48] ----
__global__ __launch_bounds__(256) void se3_hist(
    const int* __restrict__ ei, int* __restrict__ cnt,
    const float* __restrict__ wq0, const float* __restrict__ wk00,
    const float* __restrict__ wk10, float* __restrict__ wqkc) {
    int gid = blockIdx.x * 256 + threadIdx.x;
    if (gid < 1536) {
        int cp = gid / 48, c = gid % 48;
        float a = 0.f;
        if (c < 32) { for (int j = 0; j < C0O; ++j) a += wq0[cp*C0O+j] * wk00[c*C0O+j]; }
        else        { for (int j = 0; j < C0O; ++j) a += wq0[cp*C0O+j] * wk10[(c-32)*C0O+j]; }
        wqkc[gid] = a;
    }
    if (gid < NE) atomicAdd(&cnt[ei[NE + gid]], 1);
}

// ---- kC: exclusive scan of cnt[NN] -> rowptr, wptr ----
__global__ __launch_bounds__(1024) void se3_scan(
    const int* __restrict__ cnt, int* __restrict__ rowptr, int* __restrict__ wptr) {
    __shared__ int tmp[1024];
    int t = threadIdx.x;
    int base = t * 20;
    int v[20]; int s = 0;
#pragma unroll
    for (int i = 0; i < 20; ++i) {
        int idx = base + i;
        int c = (idx < NN) ? cnt[idx] : 0;
        v[i] = s; s += c;
    }
    tmp[t] = s;
    __syncthreads();
    for (int off = 1; off < 1024; off <<= 1) {
        int x = (t >= off) ? tmp[t - off] : 0;
        __syncthreads();
        tmp[t] += x;
        __syncthreads();
    }
    int tb = (t > 0) ? tmp[t - 1] : 0;
#pragma unroll
    for (int i = 0; i < 20; ++i) {
        int idx = base + i;
        if (idx < NN) { int r = tb + v[i]; rowptr[idx] = r; wptr[idx] = r; }
    }
    if (t == 1023) rowptr[NN] = NE;
}

// ---- kD: blocks [0,1250): CSR scatter; blocks [1250,6250): qvec per node ----
__global__ __launch_bounds__(256) void se3_scatqv(
    const int* __restrict__ ei, int* __restrict__ wptr, int* __restrict__ csr_src,
    const float* __restrict__ x0, const float* __restrict__ wqkc,
    float* __restrict__ qvec) {
    int b = blockIdx.x;
    if (b < 1250) {
        int e = b * 256 + threadIdx.x;
        if (e < NE) {
            int d = ei[NE + e];
            int off = atomicAdd(&wptr[d], 1);
            csr_src[off] = ei[e];
        }
    } else {
        __shared__ float sw[1536];
        for (int i = threadIdx.x; i < 1536; i += 256) sw[i] = wqkc[i];
        __syncthreads();
        int wv = threadIdx.x >> 6, lane = threadIdx.x & 63;
        int n = (b - 1250) * 4 + wv;
        float x0v = (lane < 32) ? x0[n * 32 + lane] : 0.f;
        int li = (lane < 48) ? lane : 0;
        float qh = 0.f;
        for (int cp = 0; cp < 32; ++cp)
            qh += __shfl(x0v, cp) * sw[cp * 48 + li];
        if (lane < 48) qvec[n * 48 + lane] = qh;
    }
}

// ---- kF: per-node attention, 1 wave/node, 4 waves/block, epilogue in-kernel.
//      16-edge chunks staged to LDS rows[e][80] = [x0(32)|x1(48)];
//      Y and w live in REGISTERS (all 4 lanes of an edge compute Y; Phase B
//      gets them via __shfl from lane 4e) — no cross-lane LDS flow without
//      self-alias. Explicit lds_fence() between LDS phases (wave-sync idiom
//      requires s_waitcnt lgkmcnt(0) the compiler won't insert for cross-lane
//      deps it cannot see). ----
__global__ __launch_bounds__(256) void se3_fused(
    const float* __restrict__ x0, const float* __restrict__ x1,
    const float* __restrict__ pos, const float* __restrict__ qvec,
    const int* __restrict__ rowptr, const int* __restrict__ csr_src,
    const float* __restrict__ wv00, const float* __restrict__ wv10,
    const float* __restrict__ wv01, const float* __restrict__ wv11,
    const float* __restrict__ ws0, const float* __restrict__ ws1,
    const int* __restrict__ flag, void* __restrict__ out) {
    __shared__ __align__(16) float rows[4][16][80];
    __shared__ float sq[4][48];
    __shared__ float sc[4][288];
    __shared__ float sM0[80][64];   // rows: 0-31 Wv00, 32-47 Wv10, 48-79 Wself0
    __shared__ float sM1[64][16];   // rows: 0-15 Wv11, 16-47 Wv01, 48-63 Wself1
    int tid = threadIdx.x;
    for (int i = tid; i < 5120; i += 256) {
        int r = i >> 6, j = i & 63;
        sM0[r][j] = (r < 32) ? wv00[r*64+j] : (r < 48) ? wv10[(r-32)*64+j] : ws0[(r-48)*64+j];
    }
    for (int i = tid; i < 1024; i += 256) {
        int r = i >> 4, f = i & 15;
        sM1[r][f] = (r < 16) ? wv11[r*16+f] : (r < 48) ? wv01[(r-16)*16+f] : ws1[(r-48)*16+f];
    }
    __syncthreads();

    int wv = tid >> 6, lane = tid & 63;
    int n = blockIdx.x * 4 + wv;                 // grid 5000 -> exactly NN waves
    float (*R)[80] = rows[wv];
    float* q = sq[wv];
    if (lane < 48) q[lane] = qvec[(size_t)n * 48 + lane];
    float pnx = pos[n*3], pny = pos[n*3+1], pnz = pos[n*3+2];
    int p0 = rowptr[n], deg = rowptr[n+1] - p0;

    float m = -INFINITY, zz = 0.f;
    float aggA = 0.f, aggB = 0.f, Cx = 0.f, Cy = 0.f, Cz = 0.f;
    int e4 = lane >> 2, j4 = lane & 3;
    int cc = (lane >= 32 && lane < 48) ? (lane - 32) : 0;

    for (int base = 0; base < deg; base += 16) {
        int nch = min(16, deg - base);
        float Yx = 0.f, Yy = 0.f, Yz = 0.f;
        // ---- stage: 4 lanes per edge; Y computed by ALL 4 lanes into regs ----
        if (e4 < nch) {
            int s_e = csr_src[p0 + base + e4];
            float rx = pnx - pos[s_e*3], ry = pny - pos[s_e*3+1], rz = pnz - pos[s_e*3+2];
            float inv = 1.f / (sqrtf(rx*rx + ry*ry + rz*rz) + EPSF);
            Yx = rx*inv; Yy = ry*inv; Yz = rz*inv;
            const float4* px0 = (const float4*)(x0 + (size_t)s_e * 32);
            float4 a0 = px0[j4*2], a1 = px0[j4*2+1];
            *(float4*)&R[e4][j4*8]     = a0;
            *(float4*)&R[e4][j4*8+4]   = a1;
            const float4* px1 = (const float4*)(x1 + (size_t)s_e * 48);
            float4 b0 = px1[j4*3], b1 = px1[j4*3+1], b2 = px1[j4*3+2];
            *(float4*)&R[e4][32+j4*12]   = b0;
            *(float4*)&R[e4][32+j4*12+4] = b1;
            *(float4*)&R[e4][32+j4*12+8] = b2;
        }
        lds_fence();   // stage writes visible before cross-lane reads
        // ---- logits: lane (e4,j4) covers features c = j4+4k; Y from own regs ----
        float part = 0.f;
        if (e4 < nch) {
#pragma unroll
            for (int k = 0; k < 12; ++k) {
                int c = j4 + 4*k;
                float kv;
                if (c < 32) kv = R[e4][c];
                else {
                    int c1 = c - 32;
                    kv = R[e4][32+3*c1]*Yx + R[e4][32+3*c1+1]*Yy + R[e4][32+3*c1+2]*Yz;
                }
                part += kv * q[c];
            }
        }
        part += __shfl_xor(part, 1);
        part += __shfl_xor(part, 2);
        float lg = (e4 < nch) ? part * 0.125f : -INFINITY;   // 1/sqrt(64)
        float mc = lg;
        mc = fmaxf(mc, __shfl_xor(mc, 4));
        mc = fmaxf(mc, __shfl_xor(mc, 8));
        mc = fmaxf(mc, __shfl_xor(mc, 16));
        mc = fmaxf(mc, __shfl_xor(mc, 32));
        float nm = fmaxf(m, mc);
        float f0 = __expf(m - nm);               // first chunk: exp(-inf)=0
        float w  = (e4 < nch) ? __expf(lg - nm) : 0.f;
        float sw = (j4 == 0) ? w : 0.f;
        sw += __shfl_xor(sw, 1);  sw += __shfl_xor(sw, 2);
        sw += __shfl_xor(sw, 4);  sw += __shfl_xor(sw, 8);
        sw += __shfl_xor(sw, 16); sw += __shfl_xor(sw, 32);
        zz = zz * f0 + sw;
        m = nm;
        aggA *= f0; aggB *= f0; Cx *= f0; Cy *= f0; Cz *= f0;
        // ---- Phase B: lane = feature; w/Y broadcast from lane 4e (registers) ----
#pragma unroll 4
        for (int e = 0; e < nch; ++e) {
            float we = __shfl(w, e * 4);
            float Y0 = __shfl(Yx, e * 4);
            float Y1 = __shfl(Yy, e * 4);
            float Y2 = __shfl(Yz, e * 4);
            float x1v = (lane < 48) ? R[e][32 + lane] : 0.f;
            if (lane < 32) {
                float wx = we * R[e][lane];
                aggA += wx;
                Cx += wx * Y0; Cy += wx * Y1; Cz += wx * Y2;
            } else if (lane < 48) {
                float xd = R[e][32+3*cc]*Y0 + R[e][32+3*cc+1]*Y1 + R[e][32+3*cc+2]*Y2;
                aggA += we * xd;
            }
            aggB += we * x1v;
        }
        lds_fence();   // Phase-B reads done before next chunk overwrites R
    }

    // ---- epilogue: dedicated sc scratch (round-4-proven layout) ----
    float invz = 1.f / (zz + EPSF);
    float* scw = sc[wv];
    // feat rows: [0-47] = [a0agg | dotagg], [48-79] = x0n
    // G rows (3r+d layout at 96+): [96-143] x1agg, [144-239] C, [240-287] x1n
    if (lane < 48) {
        scw[lane]       = aggA * invz;
        scw[96 + lane]  = aggB * invz;                 // x1agg, layout 3c+d
        scw[240 + lane] = x1[(size_t)n * 48 + lane];   // x1n
    }
    if (lane < 32) {
        scw[48 + lane] = x0[(size_t)n * 32 + lane];    // x0n
        scw[144 + lane * 3 + 0] = Cx * invz;
        scw[144 + lane * 3 + 1] = Cy * invz;
        scw[144 + lane * 3 + 2] = Cz * invz;
    }
    lds_fence();   // scratch writes visible before cross-lane reads
    int isf32 = *flag;
    float o0 = 0.f;
    for (int r = 0; r < 80; ++r) o0 += scw[r] * sM0[r][lane];
    int f = lane / 3, d = lane - 3 * f;
    float o1 = 0.f;
    if (lane < 48) {
        for (int r = 0; r < 64; ++r) o1 += scw[96 + 3 * r + d] * sM1[r][f];
    }

    if (isf32) {
        ((float*)out)[(size_t)n * 64 + lane] = o0;
        if (lane < 48) ((float*)out)[(size_t)NN * 64 + (size_t)n * 48 + lane] = o1;
    } else {
        ((bf16*)out)[(size_t)n * 64 + lane] = __float2bfloat16(o0);
        if (lane < 48) ((bf16*)out)[(size_t)NN * 64 + (size_t)n * 48 + lane] = __float2bfloat16(o1);
    }
}

extern "C" void kernel_launch(void* const* d_in, const int* in_sizes, int n_in,
                              void* d_out, int out_size, void* d_ws, size_t ws_size,
                              hipStream_t stream) {
    const int* ei = (const int*)d_in[3];

    int* flag  = (int*)d_ws;
    float* ws  = (float*)d_ws + 16;
    float* x0f  = ws;                 // 640000
    float* x1f  = x0f + 640000;       // 960000
    float* posf = x1f + 960000;       // 60000
    float* wq0    = posf + 60000;     // 2048
    float* wk00   = wq0 + 2048;       // 2048
    float* wk10   = wk00 + 2048;      // 1024
    float* wv00   = wk10 + 1024;      // 2048
    float* wv10   = wv00 + 2048;      // 1024
    float* wv01   = wv10 + 1024;      // 512
    float* wv11   = wv01 + 512;       // 256
    float* wself0 = wv11 + 256;       // 2048
    float* wself1 = wself0 + 2048;    // 256
    float* wqkc = ws + STAGE_TOTAL;           // 1536
    int* cnt     = (int*)(wqkc + 1536);       // NN
    int* rowptr  = cnt + NN;                  // NN+1
    int* wptr    = rowptr + NN + 1;           // NN
    int* csr_src = wptr + NN;                 // NE
    float* qvec  = (float*)(csr_src + NE);    // NN*48  (total ~12.05 MB, proven)

    se3_convert<<<1633, 256, 0, stream>>>(d_in[0], d_in[1], d_in[2],
        d_in[4], d_in[5], d_in[6], d_in[7], d_in[8], d_in[9], d_in[10], d_in[11], d_in[12],
        flag, ws, cnt);
    se3_hist<<<1250, 256, 0, stream>>>(ei, cnt, wq0, wk00, wk10, wqkc);
    se3_scan<<<1, 1024, 0, stream>>>(cnt, rowptr, wptr);
    se3_scatqv<<<6250, 256, 0, stream>>>(ei, wptr, csr_src, x0f, wqkc, qvec);
    se3_fused<<<5000, 256, 0, stream>>>(x0f, x1f, posf, qvec, rowptr, csr_src,
        wv00, wv10, wv01, wv11, wself0, wself1, flag, d_out);
}